// Round 15
// baseline (107.705 us; speedup 1.0000x reference)
//
#include <hip/hip_runtime.h>
#include <cstdint>
#include <cstddef>

#define LRALPHA 0.1f
static constexpr int NR = 8192;      // N and Na
static constexpr int EF = 256;
static constexpr int IN_F = 512;
static constexpr int OUT_F = 512;
static constexpr int KP2 = 1024;     // fp16 split-2, k'-interleaved [ah,al]
static constexpr int NCH = 128;      // chunks for column scans
static constexpr int CHR = 64;       // rows per chunk (NCH*CHR = 8192)

typedef __attribute__((ext_vector_type(8))) _Float16 f16x8;
typedef __attribute__((ext_vector_type(4))) float f32x4;

// ---- fused prep: s1/s2 dots (blocks 0..4095) + B pack ----
__global__ __launch_bounds__(256) void k_prep(const float* __restrict__ feat_edge,
                                              const float* __restrict__ feat_edge_a,
                                              const float* __restrict__ att,
                                              const float* __restrict__ W,
                                              float* __restrict__ s1,
                                              float* __restrict__ s2,
                                              short* __restrict__ B3t) {
  int b = blockIdx.x;
  if (b < 4096) {
    int vrow = b * 4 + (threadIdx.x >> 6);
    int lane = threadIdx.x & 63;
    const float* feat; const float* av; float* outp; int row;
    if (vrow < NR) { row = vrow; feat = feat_edge; av = att; outp = s1; }
    else { row = vrow - NR; feat = feat_edge_a; av = att + EF; outp = s2; }
    float4 f = reinterpret_cast<const float4*>(feat + (size_t)row * EF)[lane];
    float4 a = reinterpret_cast<const float4*>(av)[lane];
    float d = f.x * a.x + f.y * a.y + f.z * a.z + f.w * a.w;
#pragma unroll
    for (int off = 32; off > 0; off >>= 1) d += __shfl_xor(d, off);
    if (lane == 0) outp[row] = d;
  } else {
    int i = (b - 4096) * 256 + threadIdx.x;  // < 512*512
    int n = i >> 9, k = i & 511;
    float x = W[(size_t)k * OUT_F + n];
    _Float16 h = (_Float16)x;
    unsigned short u = __builtin_bit_cast(unsigned short, h);
    unsigned int w = (unsigned int)u | ((unsigned int)u << 16);
    *reinterpret_cast<unsigned int*>(B3t + (size_t)n * KP2 + 2 * k) = w;
  }
}

// ---- GEMM (blocks 0..1023, R12/R14 verified) + rank (blocks 1024..2047, R14 verified)
// Co-launched: rank's pure-LDS blocks fill gemm's barrier-stall cycles.
// LDS union 64KB -> 2 blocks/CU.
struct SReg4 { float4 a0, a1, a2, a3; int4 b0, b1, b2, b3; };

__device__ __forceinline__ int swz(int row, int slot) {
  return (row & ~7) | ((row & 7) ^ (slot & 7));
}

__global__ __launch_bounds__(256, 2) void k_gemmrank(const float* __restrict__ A,
                                                     const short* __restrict__ B3t,
                                                     float* __restrict__ Wh,
                                                     const float* __restrict__ s2,
                                                     float* __restrict__ s2s, int* __restrict__ perm,
                                                     float* __restrict__ eaA, float* __restrict__ ebA) {
  __shared__ int4 smem[4096];   // 64 KB union
  const int tid = threadIdx.x;
  int bid = blockIdx.x;
  if (bid < 1024) {
    short* lA = (short*)smem;           // [2][8192] shorts
    short* lB = (short*)smem + 16384;
    const int wid = tid >> 6, lane = tid & 63;
    const int wr = wid >> 1, wc = wid & 1;
    int xcd = bid & 7, loc = bid >> 3;
    int mb = (xcd << 4) | (loc >> 3), nb = loc & 7;   // XCD band: A-chunk L2-resident
    const int m0 = mb * 64, n0 = nb * 64;
    const int fr = lane & 15, g = lane >> 4;

    const int srow = tid >> 2, q = tid & 3;
    const float* gA = A + (size_t)(m0 + srow) * IN_F + q * 16;
    const short* gB = B3t + (size_t)(n0 + srow) * KP2 + q * 32;
    int wA[4];
#pragma unroll
    for (int j = 0; j < 4; ++j) {
      int s = 4 * q + j;
      wA[j] = s * 512 + swz(srow, s) * 8;
    }

    f32x4 acc[2][2] = {};

    auto loadR = [&](SReg4& s, int t) {
      const float* pa = gA + t * 64;
      s.a0 = *reinterpret_cast<const float4*>(pa);
      s.a1 = *reinterpret_cast<const float4*>(pa + 4);
      s.a2 = *reinterpret_cast<const float4*>(pa + 8);
      s.a3 = *reinterpret_cast<const float4*>(pa + 12);
      const short* pb = gB + t * 128;
      s.b0 = *reinterpret_cast<const int4*>(pb);
      s.b1 = *reinterpret_cast<const int4*>(pb + 8);
      s.b2 = *reinterpret_cast<const int4*>(pb + 16);
      s.b3 = *reinterpret_cast<const int4*>(pb + 24);
    };

    auto cvt4 = [](float4 p) -> int4 {
      float xs[4] = {p.x, p.y, p.z, p.w};
      int out[4];
#pragma unroll
      for (int e = 0; e < 4; ++e) {
        _Float16 h = (_Float16)xs[e];
        _Float16 l = (_Float16)(xs[e] - (float)h);
        unsigned short uh = __builtin_bit_cast(unsigned short, h);
        unsigned short ul = __builtin_bit_cast(unsigned short, l);
        out[e] = (int)uh | ((int)ul << 16);
      }
      int4 r; r.x = out[0]; r.y = out[1]; r.z = out[2]; r.w = out[3];
      return r;
    };

    auto writeL = [&](int buf, SReg4& s) {
      *reinterpret_cast<int4*>(&lA[buf * 8192 + wA[0]]) = cvt4(s.a0);
      *reinterpret_cast<int4*>(&lA[buf * 8192 + wA[1]]) = cvt4(s.a1);
      *reinterpret_cast<int4*>(&lA[buf * 8192 + wA[2]]) = cvt4(s.a2);
      *reinterpret_cast<int4*>(&lA[buf * 8192 + wA[3]]) = cvt4(s.a3);
      *reinterpret_cast<int4*>(&lB[buf * 8192 + wA[0]]) = s.b0;
      *reinterpret_cast<int4*>(&lB[buf * 8192 + wA[1]]) = s.b1;
      *reinterpret_cast<int4*>(&lB[buf * 8192 + wA[2]]) = s.b2;
      *reinterpret_cast<int4*>(&lB[buf * 8192 + wA[3]]) = s.b3;
    };

    auto compute = [&](int buf) {
#pragma unroll
      for (int ks = 0; ks < 4; ++ks) {
        int s = ks * 4 + g;
        f16x8 af[2], bv[2];
#pragma unroll
        for (int m = 0; m < 2; ++m) {
          int row = wr * 32 + m * 16 + fr;
          af[m] = *reinterpret_cast<const f16x8*>(&lA[buf * 8192 + s * 512 + swz(row, s) * 8]);
        }
#pragma unroll
        for (int n = 0; n < 2; ++n) {
          int row = wc * 32 + n * 16 + fr;
          bv[n] = *reinterpret_cast<const f16x8*>(&lB[buf * 8192 + s * 512 + swz(row, s) * 8]);
        }
#pragma unroll
        for (int m = 0; m < 2; ++m)
#pragma unroll
          for (int n = 0; n < 2; ++n)
            acc[m][n] = __builtin_amdgcn_mfma_f32_16x16x32_f16(af[m], bv[n], acc[m][n], 0, 0, 0);
      }
    };

    SReg4 SA, SB;
    loadR(SA, 0); loadR(SB, 1);
    writeL(0, SA);
    loadR(SA, 2);
    __syncthreads();

    for (int t = 0; t < 4; t += 2) {
      writeL(1, SB); loadR(SB, t + 3);
      compute(0); __syncthreads();
      writeL(0, SA); loadR(SA, t + 4);
      compute(1); __syncthreads();
    }
    writeL(1, SB); loadR(SB, 7);
    compute(0); __syncthreads();
    writeL(0, SA);
    compute(1); __syncthreads();
    writeL(1, SB);
    compute(0); __syncthreads();
    compute(1);

#pragma unroll
    for (int m = 0; m < 2; ++m) {
#pragma unroll
      for (int n = 0; n < 2; ++n) {
        int row = m0 + wr * 32 + m * 16 + g * 4;   // C/D: row=(lane>>4)*4+reg
        int col = n0 + wc * 32 + n * 16 + fr;      //      col=lane&15
#pragma unroll
        for (int r = 0; r < 4; ++r)
          Wh[(size_t)(row + r) * OUT_F + col] = acc[m][n][r];
      }
    }
  } else {
    // ---- rank: 32 lanes/key, aligned padded LDS, unsigned-monotone keys (R14) ----
    unsigned int* ls = (unsigned int*)smem;  // 32*260 uints = 33,280 B
#pragma unroll
    for (int k = 0; k < 8; ++k) {
      int q = tid + 256 * k;                  // float4 index 0..2047
      int p = q >> 6, i = q & 63;
      uint4 u = reinterpret_cast<const uint4*>(s2)[q];
      uint4 v;
      v.x = (u.x >> 31) ? ~u.x : (u.x | 0x80000000u);
      v.y = (u.y >> 31) ? ~u.y : (u.y | 0x80000000u);
      v.z = (u.z >> 31) ? ~u.z : (u.z | 0x80000000u);
      v.w = (u.w >> 31) ? ~u.w : (u.w | 0x80000000u);
      *reinterpret_cast<uint4*>(&ls[p * 260 + i * 4]) = v;
    }
    __syncthreads();

    int ki = (bid - 1024) * 8 + (tid >> 5);  // 1024 rank blocks x 8 keys
    int part = tid & 31;                     // 32 lanes share one key
    unsigned int key = ls[(ki >> 8) * 260 + (ki & 255)];
    int rank = 0;
    const int base = part * 260;
    int jbase = part * 256;
#pragma unroll 8
    for (int q = 0; q < 64; ++q) {
      uint4 v = *reinterpret_cast<const uint4*>(&ls[base + q * 4]);
      int j = jbase + q * 4;
      rank += (v.x < key) || (v.x == key && (j + 0) < ki);
      rank += (v.y < key) || (v.y == key && (j + 1) < ki);
      rank += (v.z < key) || (v.z == key && (j + 2) < ki);
      rank += (v.w < key) || (v.w == key && (j + 3) < ki);
    }
    rank += __shfl_xor(rank, 1);
    rank += __shfl_xor(rank, 2);
    rank += __shfl_xor(rank, 4);
    rank += __shfl_xor(rank, 8);
    rank += __shfl_xor(rank, 16);
    if (part == 0) {
      float kf = s2[ki];
      s2s[rank] = kf; perm[rank] = ki;
      eaA[rank] = expf(kf); ebA[rank] = expf(LRALPHA * kf);
    }
  }
}

// ---- passA: chunk sums [chunk][col] (+ block (NCH,0): scalar scans; R10-verified) ----
__global__ __launch_bounds__(256) void k_passA(const float* __restrict__ Wh,
                                               const float* __restrict__ eaA,
                                               const float* __restrict__ ebA,
                                               const int* __restrict__ perm,
                                               float* __restrict__ chunkA, float* __restrict__ chunkB,
                                               float* __restrict__ sufa, float* __restrict__ preb) {
  int t = threadIdx.x;
  if (blockIdx.x == NCH) {
    if (blockIdx.y != 0) return;
    int lane = t & 63, w = t >> 6;
    float sa = 0.f, sb = 0.f;
#pragma unroll
    for (int q = 0; q < 8; ++q) {
      float4 va = reinterpret_cast<const float4*>(eaA)[t * 8 + q];
      float4 vb = reinterpret_cast<const float4*>(ebA)[t * 8 + q];
      sa += va.x + va.y + va.z + va.w;
      sb += vb.x + vb.y + vb.z + vb.w;
    }
    float pb = sb;
#pragma unroll
    for (int off = 1; off < 64; off <<= 1) { float v = __shfl_up(pb, off); if (lane >= off) pb += v; }
    float pa = sa;
#pragma unroll
    for (int off = 1; off < 64; off <<= 1) { float v = __shfl_down(pa, off); if (lane < 64 - off) pa += v; }
    __shared__ float wtb[4], wta[4];
    if (lane == 63) wtb[w] = pb;
    if (lane == 0)  wta[w] = pa;
    __syncthreads();
    if (t == 0) {
      float rb = 0.f;
      for (int i = 0; i < 4; ++i) { float tmp = wtb[i]; wtb[i] = rb; rb += tmp; }
      float ra = 0.f;
      for (int i = 3; i >= 0; --i) { float tmp = wta[i]; wta[i] = ra; ra += tmp; }
    }
    __syncthreads();
    float run = wtb[w] + (pb - sb);
#pragma unroll
    for (int q = 0; q < 8; ++q) {
      float4 vb = reinterpret_cast<const float4*>(ebA)[t * 8 + q];
      float e4[4] = {vb.x, vb.y, vb.z, vb.w};
#pragma unroll
      for (int e = 0; e < 4; ++e) { preb[t * 32 + q * 4 + e] = run; run += e4[e]; }
    }
    if (t == 255) preb[NR] = run;
    run = wta[w] + (pa - sa);
#pragma unroll
    for (int q = 7; q >= 0; --q) {
      float4 va = reinterpret_cast<const float4*>(eaA)[t * 8 + q];
      float e4[4] = {va.x, va.y, va.z, va.w};
#pragma unroll
      for (int e = 3; e >= 0; --e) { run += e4[e]; sufa[t * 32 + q * 4 + e] = run; }
    }
    if (t == 0) sufa[NR] = 0.f;
    return;
  }
  int chunk = blockIdx.x;
  int col = blockIdx.y * 256 + t;
  float accA = 0.f, accB = 0.f;
  int r0 = chunk * CHR;
  for (int rl = 0; rl < CHR; ++rl) {
    int r = r0 + rl;
    float v = Wh[(size_t)perm[r] * OUT_F + col];
    accA += eaA[r] * v;
    accB += ebA[r] * v;
  }
  chunkA[chunk * OUT_F + col] = accA;
  chunkB[chunk * OUT_F + col] = accB;
}

// ---- passC: self-base (R10-verified) + per-row scans ----
__global__ __launch_bounds__(256) void k_passC(const float* __restrict__ Wh,
                                               const float* __restrict__ eaA,
                                               const float* __restrict__ ebA,
                                               const int* __restrict__ perm,
                                               const float* __restrict__ chunkA,
                                               const float* __restrict__ chunkB,
                                               float* __restrict__ SufA, float* __restrict__ PreB) {
  int chunk = blockIdx.x;
  int col = blockIdx.y * 256 + threadIdx.x;
  float bA = 0.f, bB = 0.f;
  for (int cp = chunk + 1; cp < NCH; ++cp) bA += chunkA[cp * OUT_F + col];
  for (int cp = 0; cp < chunk; ++cp) bB += chunkB[cp * OUT_F + col];
  int r0 = chunk * CHR;
  float acc = 0.f;
  for (int rl = CHR - 1; rl >= 0; --rl) {   // suffix incl.
    int r = r0 + rl;
    float v = Wh[(size_t)perm[r] * OUT_F + col];
    acc += eaA[r] * v;
    SufA[(size_t)r * OUT_F + col] = acc + bA;
  }
  acc = 0.f;
  for (int rl = 0; rl < CHR; ++rl) {        // prefix excl.
    int r = r0 + rl;
    float v = Wh[(size_t)perm[r] * OUT_F + col];
    PreB[(size_t)r * OUT_F + col] = acc + bB;
    acc += ebA[r] * v;
  }
  if (chunk == NCH - 1) {
    SufA[(size_t)NR * OUT_F + col] = 0.f;
    PreB[(size_t)NR * OUT_F + col] = acc + bB;
  }
}

// ---- per-row: binary search threshold rank, combine, elu ----
__global__ __launch_bounds__(256) void k_final(const float* __restrict__ s1,
                                               const float* __restrict__ s2s,
                                               const float* __restrict__ sufa,
                                               const float* __restrict__ preb,
                                               const float* __restrict__ SufA,
                                               const float* __restrict__ PreB,
                                               float* __restrict__ out) {
  int row = blockIdx.x * 4 + (threadIdx.x >> 6);
  int lane = threadIdx.x & 63;
  float sv = s1[row];
  float t = -sv;
  int lo = 0, hi = NR;
  while (lo < hi) {  // first index with s2s[idx] > t
    int mid = (lo + hi) >> 1;
    if (s2s[mid] > t) hi = mid; else lo = mid + 1;
  }
  float E1 = expf(sv), E1a = expf(LRALPHA * sv);
  float Z = E1 * sufa[lo] + E1a * preb[lo];
  const float* rA = SufA + (size_t)lo * OUT_F;
  const float* rB = PreB + (size_t)lo * OUT_F;
#pragma unroll
  for (int e = 0; e < 8; ++e) {
    int kc = e * 64 + lane;
    float num = E1 * rA[kc] + E1a * rB[kc];
    float h = num / Z;
    out[(size_t)row * OUT_F + kc] = (h > 0.f) ? h : expm1f(h);
  }
}

extern "C" void kernel_launch(void* const* d_in, const int* in_sizes, int n_in,
                              void* d_out, int out_size, void* d_ws, size_t ws_size,
                              hipStream_t stream) {
  (void)in_sizes; (void)n_in; (void)out_size; (void)ws_size;
  const float* feat_edge   = (const float*)d_in[0];
  const float* feat_edge_a = (const float*)d_in[1];
  const float* feat_node_a = (const float*)d_in[2];
  const float* weight      = (const float*)d_in[3];
  const float* att         = (const float*)d_in[4];
  float* out = (float*)d_out;

  char* ws = (char*)d_ws;
  size_t off = 0;
  auto alloc = [&](size_t bytes) { size_t o = off; off += (bytes + 255) & ~(size_t)255; return o; };

  float* Wh = (float*)(ws + alloc((size_t)NR * OUT_F * 4));           // 16.78 MB
  size_t regionOff = alloc((size_t)(NR + 1) * OUT_F * 4 * 2);          // 33.56 MB
  float* SufA = (float*)(ws + regionOff);
  float* PreB = (float*)(ws + regionOff + (size_t)(NR + 1) * OUT_F * 4);
  short* B3t  = (short*)(ws + regionOff);                              // 1.05 MB

  float* s1   = (float*)(ws + alloc(NR * 4));
  float* s2   = (float*)(ws + alloc(NR * 4));
  float* s2s  = (float*)(ws + alloc(NR * 4));
  int*   perm = (int*)  (ws + alloc(NR * 4));
  float* sufa = (float*)(ws + alloc((NR + 1) * 4));
  float* preb = (float*)(ws + alloc((NR + 1) * 4));
  float* eaA  = (float*)(ws + alloc(NR * 4));
  float* ebA  = (float*)(ws + alloc(NR * 4));
  float* chA  = (float*)(ws + alloc(NCH * OUT_F * 4));
  float* chB  = (float*)(ws + alloc(NCH * OUT_F * 4));

  k_prep<<<4096 + 1024, 256, 0, stream>>>(feat_edge, feat_edge_a, att, weight, s1, s2, B3t);
  k_gemmrank<<<2048, 256, 0, stream>>>(feat_node_a, B3t, Wh, s2, s2s, perm, eaA, ebA);
  k_passA<<<dim3(NCH + 1, 2), 256, 0, stream>>>(Wh, eaA, ebA, perm, chA, chB, sufa, preb);
  k_passC<<<dim3(NCH, 2), 256, 0, stream>>>(Wh, eaA, ebA, perm, chA, chB, SufA, PreB);
  k_final<<<NR / 4, 256, 0, stream>>>(s1, s2s, sufa, preb, SufA, PreB, out);
}

// Round 16
// 104.827 us; speedup vs baseline: 1.0275x; 1.0275x over previous
//
#include <hip/hip_runtime.h>
#include <cstdint>
#include <cstddef>

#define LRALPHA 0.1f
static constexpr int NR = 8192;      // N and Na
static constexpr int EF = 256;
static constexpr int IN_F = 512;
static constexpr int OUT_F = 512;
static constexpr int KP2 = 1024;     // fp16 split-2, k'-interleaved [ah,al]
static constexpr int NCH = 128;      // chunks for column scans
static constexpr int CHR = 64;       // rows per chunk (NCH*CHR = 8192)

typedef __attribute__((ext_vector_type(8))) _Float16 f16x8;
typedef __attribute__((ext_vector_type(4))) float f32x4;

// ---- fused prep: s1/s2 dots (blocks 0..4095) + B pack ----
__global__ __launch_bounds__(256) void k_prep(const float* __restrict__ feat_edge,
                                              const float* __restrict__ feat_edge_a,
                                              const float* __restrict__ att,
                                              const float* __restrict__ W,
                                              float* __restrict__ s1,
                                              float* __restrict__ s2,
                                              short* __restrict__ B3t) {
  int b = blockIdx.x;
  if (b < 4096) {
    int vrow = b * 4 + (threadIdx.x >> 6);
    int lane = threadIdx.x & 63;
    const float* feat; const float* av; float* outp; int row;
    if (vrow < NR) { row = vrow; feat = feat_edge; av = att; outp = s1; }
    else { row = vrow - NR; feat = feat_edge_a; av = att + EF; outp = s2; }
    float4 f = reinterpret_cast<const float4*>(feat + (size_t)row * EF)[lane];
    float4 a = reinterpret_cast<const float4*>(av)[lane];
    float d = f.x * a.x + f.y * a.y + f.z * a.z + f.w * a.w;
#pragma unroll
    for (int off = 32; off > 0; off >>= 1) d += __shfl_xor(d, off);
    if (lane == 0) outp[row] = d;
  } else {
    int i = (b - 4096) * 256 + threadIdx.x;  // < 512*512
    int n = i >> 9, k = i & 511;
    float x = W[(size_t)k * OUT_F + n];
    _Float16 h = (_Float16)x;
    unsigned short u = __builtin_bit_cast(unsigned short, h);
    unsigned int w = (unsigned int)u | ((unsigned int)u << 16);
    *reinterpret_cast<unsigned int*>(B3t + (size_t)n * KP2 + 2 * k) = w;
  }
}

// ---- Wh = split2(A) @ B3t^T : 128x128 tile, BK'=64, dbuf, 16 iters, 1 block/CU
// Ledger law: gemm_time ~= (blocks/CU x iters) x ~0.7us regardless of occupancy.
// 128x128 -> 256 blocks = 1/CU x 16 iters = 16 per-CU barrier-iters (was 32).
struct SReg4 { float4 a0, a1, a2, a3; int4 b0, b1, b2, b3; };

__device__ __forceinline__ int swz(int row, int slot) {
  return (row & ~7) | ((row & 7) ^ (slot & 7));
}

__global__ __launch_bounds__(256, 1) void k_gemm(const float* __restrict__ A,
                                                 const short* __restrict__ B3t,
                                                 float* __restrict__ Wh) {
  // per buffer: [slot=k'/8 (8)][row (128)][8 f16] = 8192 shorts = 16KB; A+B dbuf = 64KB
  __shared__ short lA[2][8192];
  __shared__ short lB[2][8192];
  const int tid = threadIdx.x;
  const int wid = tid >> 6, lane = tid & 63;
  const int wr = wid >> 1, wc = wid & 1;
  int bid = blockIdx.x;                       // 0..255
  int xcd = bid & 7, loc = bid >> 3;          // 32 tiles per XCD
  int mb = (xcd << 3) | (loc >> 2), nb = loc & 3;   // XCD band: 2MB A + 1MB B L2-resident
  const int m0 = mb * 128, n0 = nb * 128;
  const int fr = lane & 15, g = lane >> 4;

  // staging: 2 threads/row; thread (srow=tid>>1, h=tid&1) covers k' [h*32, h*32+32)
  const int srow = tid >> 1, h = tid & 1;
  const float* gA = A + (size_t)(m0 + srow) * IN_F + h * 16;
  const short* gB = B3t + (size_t)(n0 + srow) * KP2 + h * 32;
  int wOf[4];
#pragma unroll
  for (int j = 0; j < 4; ++j) {
    int s = h * 4 + j;
    wOf[j] = s * 1024 + swz(srow, s) * 8;
  }

  f32x4 acc[4][4] = {};

  auto loadR = [&](SReg4& s, int t) {
    const float* pa = gA + t * 32;
    s.a0 = *reinterpret_cast<const float4*>(pa);
    s.a1 = *reinterpret_cast<const float4*>(pa + 4);
    s.a2 = *reinterpret_cast<const float4*>(pa + 8);
    s.a3 = *reinterpret_cast<const float4*>(pa + 12);
    const short* pb = gB + t * 64;
    s.b0 = *reinterpret_cast<const int4*>(pb);
    s.b1 = *reinterpret_cast<const int4*>(pb + 8);
    s.b2 = *reinterpret_cast<const int4*>(pb + 16);
    s.b3 = *reinterpret_cast<const int4*>(pb + 24);
  };

  auto cvt4 = [](float4 p) -> int4 {  // 4 f32 -> 4 dwords of [ah | al]
    float xs[4] = {p.x, p.y, p.z, p.w};
    int out[4];
#pragma unroll
    for (int e = 0; e < 4; ++e) {
      _Float16 hh = (_Float16)xs[e];
      _Float16 ll = (_Float16)(xs[e] - (float)hh);
      unsigned short uh = __builtin_bit_cast(unsigned short, hh);
      unsigned short ul = __builtin_bit_cast(unsigned short, ll);
      out[e] = (int)uh | ((int)ul << 16);
    }
    int4 r; r.x = out[0]; r.y = out[1]; r.z = out[2]; r.w = out[3];
    return r;
  };

  auto writeL = [&](int buf, SReg4& s) {
    *reinterpret_cast<int4*>(&lA[buf][wOf[0]]) = cvt4(s.a0);
    *reinterpret_cast<int4*>(&lA[buf][wOf[1]]) = cvt4(s.a1);
    *reinterpret_cast<int4*>(&lA[buf][wOf[2]]) = cvt4(s.a2);
    *reinterpret_cast<int4*>(&lA[buf][wOf[3]]) = cvt4(s.a3);
    *reinterpret_cast<int4*>(&lB[buf][wOf[0]]) = s.b0;
    *reinterpret_cast<int4*>(&lB[buf][wOf[1]]) = s.b1;
    *reinterpret_cast<int4*>(&lB[buf][wOf[2]]) = s.b2;
    *reinterpret_cast<int4*>(&lB[buf][wOf[3]]) = s.b3;
  };

  auto compute = [&](int buf) {
#pragma unroll
    for (int ks = 0; ks < 2; ++ks) {
      int s = ks * 4 + g;
      f16x8 af[4], bv[4];
#pragma unroll
      for (int m = 0; m < 4; ++m) {
        int row = wr * 64 + m * 16 + fr;
        af[m] = *reinterpret_cast<const f16x8*>(&lA[buf][s * 1024 + swz(row, s) * 8]);
      }
#pragma unroll
      for (int n = 0; n < 4; ++n) {
        int row = wc * 64 + n * 16 + fr;
        bv[n] = *reinterpret_cast<const f16x8*>(&lB[buf][s * 1024 + swz(row, s) * 8]);
      }
#pragma unroll
      for (int m = 0; m < 4; ++m)
#pragma unroll
        for (int n = 0; n < 4; ++n)
          acc[m][n] = __builtin_amdgcn_mfma_f32_16x16x32_f16(af[m], bv[n], acc[m][n], 0, 0, 0);
    }
  };

  SReg4 SA, SB;
  loadR(SA, 0); loadR(SB, 1);
  writeL(0, SA);
  loadR(SA, 2);
  __syncthreads();

  for (int t = 0; t < 12; t += 2) {
    writeL(1, SB); loadR(SB, t + 3);
    compute(0); __syncthreads();
    writeL(0, SA); loadR(SA, t + 4);
    compute(1); __syncthreads();
  }
  writeL(1, SB); loadR(SB, 15);   // write 13, load 15
  compute(0); __syncthreads();    // compute 12
  writeL(0, SA);                  // write 14
  compute(1); __syncthreads();    // compute 13
  writeL(1, SB);                  // write 15
  compute(0); __syncthreads();    // compute 14
  compute(1);                     // compute 15

#pragma unroll
  for (int m = 0; m < 4; ++m) {
#pragma unroll
    for (int n = 0; n < 4; ++n) {
      int row = m0 + wr * 64 + m * 16 + g * 4;   // C/D: row=(lane>>4)*4+reg
      int col = n0 + wc * 64 + n * 16 + fr;      //      col=lane&15
#pragma unroll
      for (int r = 0; r < 4; ++r)
        Wh[(size_t)(row + r) * OUT_F + col] = acc[m][n][r];
    }
  }
}

// ---- rank: 32 lanes/key, 1024 blocks (4/CU), aligned padded LDS, unsigned keys (R14) ----
__global__ __launch_bounds__(256) void k_rank(const float* __restrict__ s2,
                                              float* __restrict__ s2s, int* __restrict__ perm,
                                              float* __restrict__ eaA, float* __restrict__ ebA) {
  __shared__ unsigned int ls[32 * 260];  // part p at ls[p*260+i]; addr 4*(65p+q) -> b128 ok
  int t = threadIdx.x;
#pragma unroll
  for (int k = 0; k < 8; ++k) {
    int q = t + 256 * k;                  // float4 index 0..2047
    int p = q >> 6, i = q & 63;
    uint4 u = reinterpret_cast<const uint4*>(s2)[q];
    uint4 v;
    v.x = (u.x >> 31) ? ~u.x : (u.x | 0x80000000u);
    v.y = (u.y >> 31) ? ~u.y : (u.y | 0x80000000u);
    v.z = (u.z >> 31) ? ~u.z : (u.z | 0x80000000u);
    v.w = (u.w >> 31) ? ~u.w : (u.w | 0x80000000u);
    *reinterpret_cast<uint4*>(&ls[p * 260 + i * 4]) = v;
  }
  __syncthreads();

  int ki = blockIdx.x * 8 + (t >> 5);    // 1024 blocks x 8 keys
  int part = t & 31;                     // 32 lanes share one key
  unsigned int key = ls[(ki >> 8) * 260 + (ki & 255)];
  int rank = 0;
  const int base = part * 260;
  int jbase = part * 256;
#pragma unroll 8
  for (int q = 0; q < 64; ++q) {
    uint4 v = *reinterpret_cast<const uint4*>(&ls[base + q * 4]);
    int j = jbase + q * 4;
    rank += (v.x < key) || (v.x == key && (j + 0) < ki);
    rank += (v.y < key) || (v.y == key && (j + 1) < ki);
    rank += (v.z < key) || (v.z == key && (j + 2) < ki);
    rank += (v.w < key) || (v.w == key && (j + 3) < ki);
  }
  rank += __shfl_xor(rank, 1);
  rank += __shfl_xor(rank, 2);
  rank += __shfl_xor(rank, 4);
  rank += __shfl_xor(rank, 8);
  rank += __shfl_xor(rank, 16);
  if (part == 0) {
    float kf = s2[ki];
    s2s[rank] = kf; perm[rank] = ki;
    eaA[rank] = expf(kf); ebA[rank] = expf(LRALPHA * kf);
  }
}

// ---- passA: chunk sums [chunk][col] (+ block (NCH,0): scalar scans; R15-verified) ----
__global__ __launch_bounds__(256) void k_passA(const float* __restrict__ Wh,
                                               const float* __restrict__ eaA,
                                               const float* __restrict__ ebA,
                                               const int* __restrict__ perm,
                                               float* __restrict__ chunkA, float* __restrict__ chunkB,
                                               float* __restrict__ sufa, float* __restrict__ preb) {
  int t = threadIdx.x;
  if (blockIdx.x == NCH) {
    if (blockIdx.y != 0) return;
    int lane = t & 63, w = t >> 6;
    float sa = 0.f, sb = 0.f;
#pragma unroll
    for (int q = 0; q < 8; ++q) {
      float4 va = reinterpret_cast<const float4*>(eaA)[t * 8 + q];
      float4 vb = reinterpret_cast<const float4*>(ebA)[t * 8 + q];
      sa += va.x + va.y + va.z + va.w;
      sb += vb.x + vb.y + vb.z + vb.w;
    }
    float pb = sb;
#pragma unroll
    for (int off = 1; off < 64; off <<= 1) { float v = __shfl_up(pb, off); if (lane >= off) pb += v; }
    float pa = sa;
#pragma unroll
    for (int off = 1; off < 64; off <<= 1) { float v = __shfl_down(pa, off); if (lane < 64 - off) pa += v; }
    __shared__ float wtb[4], wta[4];
    if (lane == 63) wtb[w] = pb;
    if (lane == 0)  wta[w] = pa;
    __syncthreads();
    if (t == 0) {
      float rb = 0.f;
      for (int i = 0; i < 4; ++i) { float tmp = wtb[i]; wtb[i] = rb; rb += tmp; }
      float ra = 0.f;
      for (int i = 3; i >= 0; --i) { float tmp = wta[i]; wta[i] = ra; ra += tmp; }
    }
    __syncthreads();
    float run = wtb[w] + (pb - sb);
#pragma unroll
    for (int q = 0; q < 8; ++q) {
      float4 vb = reinterpret_cast<const float4*>(ebA)[t * 8 + q];
      float e4[4] = {vb.x, vb.y, vb.z, vb.w};
#pragma unroll
      for (int e = 0; e < 4; ++e) { preb[t * 32 + q * 4 + e] = run; run += e4[e]; }
    }
    if (t == 255) preb[NR] = run;
    run = wta[w] + (pa - sa);
#pragma unroll
    for (int q = 7; q >= 0; --q) {
      float4 va = reinterpret_cast<const float4*>(eaA)[t * 8 + q];
      float e4[4] = {va.x, va.y, va.z, va.w};
#pragma unroll
      for (int e = 3; e >= 0; --e) { run += e4[e]; sufa[t * 32 + q * 4 + e] = run; }
    }
    if (t == 0) sufa[NR] = 0.f;
    return;
  }
  int chunk = blockIdx.x;
  int col = blockIdx.y * 256 + t;
  float accA = 0.f, accB = 0.f;
  int r0 = chunk * CHR;
  for (int rl = 0; rl < CHR; ++rl) {
    int r = r0 + rl;
    float v = Wh[(size_t)perm[r] * OUT_F + col];
    accA += eaA[r] * v;
    accB += ebA[r] * v;
  }
  chunkA[chunk * OUT_F + col] = accA;
  chunkB[chunk * OUT_F + col] = accB;
}

// ---- passC: self-base (coalesced L2 reads of chunk sums; R15-verified) ----
__global__ __launch_bounds__(256) void k_passC(const float* __restrict__ Wh,
                                               const float* __restrict__ eaA,
                                               const float* __restrict__ ebA,
                                               const int* __restrict__ perm,
                                               const float* __restrict__ chunkA,
                                               const float* __restrict__ chunkB,
                                               float* __restrict__ SufA, float* __restrict__ PreB) {
  int chunk = blockIdx.x;
  int col = blockIdx.y * 256 + threadIdx.x;
  float bA = 0.f, bB = 0.f;
  for (int cp = chunk + 1; cp < NCH; ++cp) bA += chunkA[cp * OUT_F + col];
  for (int cp = 0; cp < chunk; ++cp) bB += chunkB[cp * OUT_F + col];
  int r0 = chunk * CHR;
  float acc = 0.f;
  for (int rl = CHR - 1; rl >= 0; --rl) {   // suffix incl.
    int r = r0 + rl;
    float v = Wh[(size_t)perm[r] * OUT_F + col];
    acc += eaA[r] * v;
    SufA[(size_t)r * OUT_F + col] = acc + bA;
  }
  acc = 0.f;
  for (int rl = 0; rl < CHR; ++rl) {        // prefix excl.
    int r = r0 + rl;
    float v = Wh[(size_t)perm[r] * OUT_F + col];
    PreB[(size_t)r * OUT_F + col] = acc + bB;
    acc += ebA[r] * v;
  }
  if (chunk == NCH - 1) {
    SufA[(size_t)NR * OUT_F + col] = 0.f;
    PreB[(size_t)NR * OUT_F + col] = acc + bB;
  }
}

// ---- per-row: binary search threshold rank, combine, elu ----
__global__ __launch_bounds__(256) void k_final(const float* __restrict__ s1,
                                               const float* __restrict__ s2s,
                                               const float* __restrict__ sufa,
                                               const float* __restrict__ preb,
                                               const float* __restrict__ SufA,
                                               const float* __restrict__ PreB,
                                               float* __restrict__ out) {
  int row = blockIdx.x * 4 + (threadIdx.x >> 6);
  int lane = threadIdx.x & 63;
  float sv = s1[row];
  float t = -sv;
  int lo = 0, hi = NR;
  while (lo < hi) {  // first index with s2s[idx] > t
    int mid = (lo + hi) >> 1;
    if (s2s[mid] > t) hi = mid; else lo = mid + 1;
  }
  float E1 = expf(sv), E1a = expf(LRALPHA * sv);
  float Z = E1 * sufa[lo] + E1a * preb[lo];
  const float* rA = SufA + (size_t)lo * OUT_F;
  const float* rB = PreB + (size_t)lo * OUT_F;
#pragma unroll
  for (int e = 0; e < 8; ++e) {
    int kc = e * 64 + lane;
    float num = E1 * rA[kc] + E1a * rB[kc];
    float h = num / Z;
    out[(size_t)row * OUT_F + kc] = (h > 0.f) ? h : expm1f(h);
  }
}

extern "C" void kernel_launch(void* const* d_in, const int* in_sizes, int n_in,
                              void* d_out, int out_size, void* d_ws, size_t ws_size,
                              hipStream_t stream) {
  (void)in_sizes; (void)n_in; (void)out_size; (void)ws_size;
  const float* feat_edge   = (const float*)d_in[0];
  const float* feat_edge_a = (const float*)d_in[1];
  const float* feat_node_a = (const float*)d_in[2];
  const float* weight      = (const float*)d_in[3];
  const float* att         = (const float*)d_in[4];
  float* out = (float*)d_out;

  char* ws = (char*)d_ws;
  size_t off = 0;
  auto alloc = [&](size_t bytes) { size_t o = off; off += (bytes + 255) & ~(size_t)255; return o; };

  float* Wh = (float*)(ws + alloc((size_t)NR * OUT_F * 4));           // 16.78 MB
  size_t regionOff = alloc((size_t)(NR + 1) * OUT_F * 4 * 2);          // 33.56 MB
  float* SufA = (float*)(ws + regionOff);
  float* PreB = (float*)(ws + regionOff + (size_t)(NR + 1) * OUT_F * 4);
  short* B3t  = (short*)(ws + regionOff);                              // 1.05 MB

  float* s1   = (float*)(ws + alloc(NR * 4));
  float* s2   = (float*)(ws + alloc(NR * 4));
  float* s2s  = (float*)(ws + alloc(NR * 4));
  int*   perm = (int*)  (ws + alloc(NR * 4));
  float* sufa = (float*)(ws + alloc((NR + 1) * 4));
  float* preb = (float*)(ws + alloc((NR + 1) * 4));
  float* eaA  = (float*)(ws + alloc(NR * 4));
  float* ebA  = (float*)(ws + alloc(NR * 4));
  float* chA  = (float*)(ws + alloc(NCH * OUT_F * 4));
  float* chB  = (float*)(ws + alloc(NCH * OUT_F * 4));

  k_prep<<<4096 + 1024, 256, 0, stream>>>(feat_edge, feat_edge_a, att, weight, s1, s2, B3t);
  k_gemm<<<256, 256, 0, stream>>>(feat_node_a, B3t, Wh);
  k_rank<<<NR / 8, 256, 0, stream>>>(s2, s2s, perm, eaA, ebA);
  k_passA<<<dim3(NCH + 1, 2), 256, 0, stream>>>(Wh, eaA, ebA, perm, chA, chB, sufa, preb);
  k_passC<<<dim3(NCH, 2), 256, 0, stream>>>(Wh, eaA, ebA, perm, chA, chB, SufA, PreB);
  k_final<<<NR / 4, 256, 0, stream>>>(s1, s2s, sufa, preb, SufA, PreB, out);
}

// Round 17
// 104.042 us; speedup vs baseline: 1.0352x; 1.0076x over previous
//
#include <hip/hip_runtime.h>
#include <cstdint>
#include <cstddef>

#define LRALPHA 0.1f
static constexpr int NR = 8192;      // N and Na
static constexpr int EF = 256;
static constexpr int IN_F = 512;
static constexpr int OUT_F = 512;
static constexpr int KP2 = 1024;     // fp16 split-2, k'-interleaved [ah,al]
static constexpr int NCH = 128;      // chunks for column scans
static constexpr int CHR = 64;       // rows per chunk (NCH*CHR = 8192)

typedef __attribute__((ext_vector_type(8))) _Float16 f16x8;
typedef __attribute__((ext_vector_type(4))) float f32x4;

// ---- fused prep: s1/s2 dots (blocks 0..4095) + B pack ----
__global__ __launch_bounds__(256) void k_prep(const float* __restrict__ feat_edge,
                                              const float* __restrict__ feat_edge_a,
                                              const float* __restrict__ att,
                                              const float* __restrict__ W,
                                              float* __restrict__ s1,
                                              float* __restrict__ s2,
                                              short* __restrict__ B3t) {
  int b = blockIdx.x;
  if (b < 4096) {
    int vrow = b * 4 + (threadIdx.x >> 6);
    int lane = threadIdx.x & 63;
    const float* feat; const float* av; float* outp; int row;
    if (vrow < NR) { row = vrow; feat = feat_edge; av = att; outp = s1; }
    else { row = vrow - NR; feat = feat_edge_a; av = att + EF; outp = s2; }
    float4 f = reinterpret_cast<const float4*>(feat + (size_t)row * EF)[lane];
    float4 a = reinterpret_cast<const float4*>(av)[lane];
    float d = f.x * a.x + f.y * a.y + f.z * a.z + f.w * a.w;
#pragma unroll
    for (int off = 32; off > 0; off >>= 1) d += __shfl_xor(d, off);
    if (lane == 0) outp[row] = d;
  } else {
    int i = (b - 4096) * 256 + threadIdx.x;  // < 512*512
    int n = i >> 9, k = i & 511;
    float x = W[(size_t)k * OUT_F + n];
    _Float16 h = (_Float16)x;
    unsigned short u = __builtin_bit_cast(unsigned short, h);
    unsigned int w = (unsigned int)u | ((unsigned int)u << 16);
    *reinterpret_cast<unsigned int*>(B3t + (size_t)n * KP2 + 2 * k) = w;
  }
}

// ---- Wh = split2(A) @ B3t^T : 128x128 tile, BK'=64, dbuf, 16 iters, 1 block/CU ----
struct SReg4 { float4 a0, a1, a2, a3; int4 b0, b1, b2, b3; };

__device__ __forceinline__ int swz(int row, int slot) {
  return (row & ~7) | ((row & 7) ^ (slot & 7));
}

__global__ __launch_bounds__(256, 1) void k_gemm(const float* __restrict__ A,
                                                 const short* __restrict__ B3t,
                                                 float* __restrict__ Wh) {
  // per buffer: [slot=k'/8 (8)][row (128)][8 f16] = 8192 shorts = 16KB; A+B dbuf = 64KB
  __shared__ short lA[2][8192];
  __shared__ short lB[2][8192];
  const int tid = threadIdx.x;
  const int wid = tid >> 6, lane = tid & 63;
  const int wr = wid >> 1, wc = wid & 1;
  int bid = blockIdx.x;                       // 0..255
  int xcd = bid & 7, loc = bid >> 3;          // 32 tiles per XCD
  int mb = (xcd << 3) | (loc >> 2), nb = loc & 3;   // XCD band: 2MB A + 1MB B L2-resident
  const int m0 = mb * 128, n0 = nb * 128;
  const int fr = lane & 15, g = lane >> 4;

  const int srow = tid >> 1, h = tid & 1;
  const float* gA = A + (size_t)(m0 + srow) * IN_F + h * 16;
  const short* gB = B3t + (size_t)(n0 + srow) * KP2 + h * 32;
  int wOf[4];
#pragma unroll
  for (int j = 0; j < 4; ++j) {
    int s = h * 4 + j;
    wOf[j] = s * 1024 + swz(srow, s) * 8;
  }

  f32x4 acc[4][4] = {};

  auto loadR = [&](SReg4& s, int t) {
    const float* pa = gA + t * 32;
    s.a0 = *reinterpret_cast<const float4*>(pa);
    s.a1 = *reinterpret_cast<const float4*>(pa + 4);
    s.a2 = *reinterpret_cast<const float4*>(pa + 8);
    s.a3 = *reinterpret_cast<const float4*>(pa + 12);
    const short* pb = gB + t * 64;
    s.b0 = *reinterpret_cast<const int4*>(pb);
    s.b1 = *reinterpret_cast<const int4*>(pb + 8);
    s.b2 = *reinterpret_cast<const int4*>(pb + 16);
    s.b3 = *reinterpret_cast<const int4*>(pb + 24);
  };

  auto cvt4 = [](float4 p) -> int4 {  // 4 f32 -> 4 dwords of [ah | al]
    float xs[4] = {p.x, p.y, p.z, p.w};
    int out[4];
#pragma unroll
    for (int e = 0; e < 4; ++e) {
      _Float16 hh = (_Float16)xs[e];
      _Float16 ll = (_Float16)(xs[e] - (float)hh);
      unsigned short uh = __builtin_bit_cast(unsigned short, hh);
      unsigned short ul = __builtin_bit_cast(unsigned short, ll);
      out[e] = (int)uh | ((int)ul << 16);
    }
    int4 r; r.x = out[0]; r.y = out[1]; r.z = out[2]; r.w = out[3];
    return r;
  };

  auto writeL = [&](int buf, SReg4& s) {
    *reinterpret_cast<int4*>(&lA[buf][wOf[0]]) = cvt4(s.a0);
    *reinterpret_cast<int4*>(&lA[buf][wOf[1]]) = cvt4(s.a1);
    *reinterpret_cast<int4*>(&lA[buf][wOf[2]]) = cvt4(s.a2);
    *reinterpret_cast<int4*>(&lA[buf][wOf[3]]) = cvt4(s.a3);
    *reinterpret_cast<int4*>(&lB[buf][wOf[0]]) = s.b0;
    *reinterpret_cast<int4*>(&lB[buf][wOf[1]]) = s.b1;
    *reinterpret_cast<int4*>(&lB[buf][wOf[2]]) = s.b2;
    *reinterpret_cast<int4*>(&lB[buf][wOf[3]]) = s.b3;
  };

  auto compute = [&](int buf) {
#pragma unroll
    for (int ks = 0; ks < 2; ++ks) {
      int s = ks * 4 + g;
      f16x8 af[4], bv[4];
#pragma unroll
      for (int m = 0; m < 4; ++m) {
        int row = wr * 64 + m * 16 + fr;
        af[m] = *reinterpret_cast<const f16x8*>(&lA[buf][s * 1024 + swz(row, s) * 8]);
      }
#pragma unroll
      for (int n = 0; n < 4; ++n) {
        int row = wc * 64 + n * 16 + fr;
        bv[n] = *reinterpret_cast<const f16x8*>(&lB[buf][s * 1024 + swz(row, s) * 8]);
      }
#pragma unroll
      for (int m = 0; m < 4; ++m)
#pragma unroll
        for (int n = 0; n < 4; ++n)
          acc[m][n] = __builtin_amdgcn_mfma_f32_16x16x32_f16(af[m], bv[n], acc[m][n], 0, 0, 0);
    }
  };

  SReg4 SA, SB;
  loadR(SA, 0); loadR(SB, 1);
  writeL(0, SA);
  loadR(SA, 2);
  __syncthreads();

  for (int t = 0; t < 12; t += 2) {
    writeL(1, SB); loadR(SB, t + 3);
    compute(0); __syncthreads();
    writeL(0, SA); loadR(SA, t + 4);
    compute(1); __syncthreads();
  }
  writeL(1, SB); loadR(SB, 15);
  compute(0); __syncthreads();
  writeL(0, SA);
  compute(1); __syncthreads();
  writeL(1, SB);
  compute(0); __syncthreads();
  compute(1);

#pragma unroll
  for (int m = 0; m < 4; ++m) {
#pragma unroll
    for (int n = 0; n < 4; ++n) {
      int row = m0 + wr * 64 + m * 16 + g * 4;   // C/D: row=(lane>>4)*4+reg
      int col = n0 + wc * 64 + n * 16 + fr;      //      col=lane&15
#pragma unroll
      for (int r = 0; r < 4; ++r)
        Wh[(size_t)(row + r) * OUT_F + col] = acc[m][n][r];
    }
  }
}

// ---- rank: 32 lanes/key, 1024 blocks (4/CU), aligned padded LDS, unsigned keys ----
__global__ __launch_bounds__(256) void k_rank(const float* __restrict__ s2,
                                              float* __restrict__ s2s, int* __restrict__ perm,
                                              float* __restrict__ eaA, float* __restrict__ ebA) {
  __shared__ unsigned int ls[32 * 260];  // part p at ls[p*260+i]; addr 4*(65p+q) -> b128 ok
  int t = threadIdx.x;
#pragma unroll
  for (int k = 0; k < 8; ++k) {
    int q = t + 256 * k;                  // float4 index 0..2047
    int p = q >> 6, i = q & 63;
    uint4 u = reinterpret_cast<const uint4*>(s2)[q];
    uint4 v;
    v.x = (u.x >> 31) ? ~u.x : (u.x | 0x80000000u);
    v.y = (u.y >> 31) ? ~u.y : (u.y | 0x80000000u);
    v.z = (u.z >> 31) ? ~u.z : (u.z | 0x80000000u);
    v.w = (u.w >> 31) ? ~u.w : (u.w | 0x80000000u);
    *reinterpret_cast<uint4*>(&ls[p * 260 + i * 4]) = v;
  }
  __syncthreads();

  int ki = blockIdx.x * 8 + (t >> 5);    // 1024 blocks x 8 keys
  int part = t & 31;                     // 32 lanes share one key
  unsigned int key = ls[(ki >> 8) * 260 + (ki & 255)];
  int rank = 0;
  const int base = part * 260;
  int jbase = part * 256;
#pragma unroll 8
  for (int q = 0; q < 64; ++q) {
    uint4 v = *reinterpret_cast<const uint4*>(&ls[base + q * 4]);
    int j = jbase + q * 4;
    rank += (v.x < key) || (v.x == key && (j + 0) < ki);
    rank += (v.y < key) || (v.y == key && (j + 1) < ki);
    rank += (v.z < key) || (v.z == key && (j + 2) < ki);
    rank += (v.w < key) || (v.w == key && (j + 3) < ki);
  }
  rank += __shfl_xor(rank, 1);
  rank += __shfl_xor(rank, 2);
  rank += __shfl_xor(rank, 4);
  rank += __shfl_xor(rank, 8);
  rank += __shfl_xor(rank, 16);
  if (part == 0) {
    float kf = s2[ki];
    s2s[rank] = kf; perm[rank] = ki;
    eaA[rank] = expf(kf); ebA[rank] = expf(LRALPHA * kf);
  }
}

// ---- passA: chunk sums [chunk][col], v[64] register-batched (MLP=64);
//      block (NCH,0): scalar scans (R15-verified) ----
__global__ __launch_bounds__(256) void k_passA(const float* __restrict__ Wh,
                                               const float* __restrict__ eaA,
                                               const float* __restrict__ ebA,
                                               const int* __restrict__ perm,
                                               float* __restrict__ chunkA, float* __restrict__ chunkB,
                                               float* __restrict__ sufa, float* __restrict__ preb) {
  int t = threadIdx.x;
  if (blockIdx.x == NCH) {
    if (blockIdx.y != 0) return;
    int lane = t & 63, w = t >> 6;
    float sa = 0.f, sb = 0.f;
#pragma unroll
    for (int q = 0; q < 8; ++q) {
      float4 va = reinterpret_cast<const float4*>(eaA)[t * 8 + q];
      float4 vb = reinterpret_cast<const float4*>(ebA)[t * 8 + q];
      sa += va.x + va.y + va.z + va.w;
      sb += vb.x + vb.y + vb.z + vb.w;
    }
    float pb = sb;
#pragma unroll
    for (int off = 1; off < 64; off <<= 1) { float v = __shfl_up(pb, off); if (lane >= off) pb += v; }
    float pa = sa;
#pragma unroll
    for (int off = 1; off < 64; off <<= 1) { float v = __shfl_down(pa, off); if (lane < 64 - off) pa += v; }
    __shared__ float wtb[4], wta[4];
    if (lane == 63) wtb[w] = pb;
    if (lane == 0)  wta[w] = pa;
    __syncthreads();
    if (t == 0) {
      float rb = 0.f;
      for (int i = 0; i < 4; ++i) { float tmp = wtb[i]; wtb[i] = rb; rb += tmp; }
      float ra = 0.f;
      for (int i = 3; i >= 0; --i) { float tmp = wta[i]; wta[i] = ra; ra += tmp; }
    }
    __syncthreads();
    float run = wtb[w] + (pb - sb);
#pragma unroll
    for (int q = 0; q < 8; ++q) {
      float4 vb = reinterpret_cast<const float4*>(ebA)[t * 8 + q];
      float e4[4] = {vb.x, vb.y, vb.z, vb.w};
#pragma unroll
      for (int e = 0; e < 4; ++e) { preb[t * 32 + q * 4 + e] = run; run += e4[e]; }
    }
    if (t == 255) preb[NR] = run;
    run = wta[w] + (pa - sa);
#pragma unroll
    for (int q = 7; q >= 0; --q) {
      float4 va = reinterpret_cast<const float4*>(eaA)[t * 8 + q];
      float e4[4] = {va.x, va.y, va.z, va.w};
#pragma unroll
      for (int e = 3; e >= 0; --e) { run += e4[e]; sufa[t * 32 + q * 4 + e] = run; }
    }
    if (t == 0) sufa[NR] = 0.f;
    return;
  }
  int chunk = blockIdx.x;
  int col = blockIdx.y * 256 + t;
  int r0 = chunk * CHR;
  float v[CHR];
#pragma unroll
  for (int j = 0; j < CHR; ++j)
    v[j] = Wh[(size_t)perm[r0 + j] * OUT_F + col];   // 64 independent loads in flight
  float accA = 0.f, accB = 0.f;
#pragma unroll
  for (int j = 0; j < CHR; ++j) {
    accA += eaA[r0 + j] * v[j];
    accB += ebA[r0 + j] * v[j];
  }
  chunkA[chunk * OUT_F + col] = accA;
  chunkB[chunk * OUT_F + col] = accB;
}

// ---- passC: self-base + v[64] register-batched chunk (read Wh ONCE, MLP=64) ----
__global__ __launch_bounds__(256) void k_passC(const float* __restrict__ Wh,
                                               const float* __restrict__ eaA,
                                               const float* __restrict__ ebA,
                                               const int* __restrict__ perm,
                                               const float* __restrict__ chunkA,
                                               const float* __restrict__ chunkB,
                                               float* __restrict__ SufA, float* __restrict__ PreB) {
  int chunk = blockIdx.x;
  int col = blockIdx.y * 256 + threadIdx.x;
  float bA = 0.f, bB = 0.f;
  for (int cp = chunk + 1; cp < NCH; ++cp) bA += chunkA[cp * OUT_F + col];
  for (int cp = 0; cp < chunk; ++cp) bB += chunkB[cp * OUT_F + col];
  int r0 = chunk * CHR;
  float v[CHR];
#pragma unroll
  for (int j = 0; j < CHR; ++j)
    v[j] = Wh[(size_t)perm[r0 + j] * OUT_F + col];   // 64 independent loads in flight
  float acc = 0.f;
#pragma unroll
  for (int j = CHR - 1; j >= 0; --j) {   // suffix incl.
    acc += eaA[r0 + j] * v[j];
    SufA[(size_t)(r0 + j) * OUT_F + col] = acc + bA;
  }
  acc = 0.f;
#pragma unroll
  for (int j = 0; j < CHR; ++j) {        // prefix excl.
    PreB[(size_t)(r0 + j) * OUT_F + col] = acc + bB;
    acc += ebA[r0 + j] * v[j];
  }
  if (chunk == NCH - 1) {
    SufA[(size_t)NR * OUT_F + col] = 0.f;
    PreB[(size_t)NR * OUT_F + col] = acc + bB;
  }
}

// ---- per-row: binary search threshold rank, combine, elu ----
__global__ __launch_bounds__(256) void k_final(const float* __restrict__ s1,
                                               const float* __restrict__ s2s,
                                               const float* __restrict__ sufa,
                                               const float* __restrict__ preb,
                                               const float* __restrict__ SufA,
                                               const float* __restrict__ PreB,
                                               float* __restrict__ out) {
  int row = blockIdx.x * 4 + (threadIdx.x >> 6);
  int lane = threadIdx.x & 63;
  float sv = s1[row];
  float t = -sv;
  int lo = 0, hi = NR;
  while (lo < hi) {  // first index with s2s[idx] > t
    int mid = (lo + hi) >> 1;
    if (s2s[mid] > t) hi = mid; else lo = mid + 1;
  }
  float E1 = expf(sv), E1a = expf(LRALPHA * sv);
  float Z = E1 * sufa[lo] + E1a * preb[lo];
  const float* rA = SufA + (size_t)lo * OUT_F;
  const float* rB = PreB + (size_t)lo * OUT_F;
#pragma unroll
  for (int e = 0; e < 8; ++e) {
    int kc = e * 64 + lane;
    float num = E1 * rA[kc] + E1a * rB[kc];
    float h = num / Z;
    out[(size_t)row * OUT_F + kc] = (h > 0.f) ? h : expm1f(h);
  }
}

extern "C" void kernel_launch(void* const* d_in, const int* in_sizes, int n_in,
                              void* d_out, int out_size, void* d_ws, size_t ws_size,
                              hipStream_t stream) {
  (void)in_sizes; (void)n_in; (void)out_size; (void)ws_size;
  const float* feat_edge   = (const float*)d_in[0];
  const float* feat_edge_a = (const float*)d_in[1];
  const float* feat_node_a = (const float*)d_in[2];
  const float* weight      = (const float*)d_in[3];
  const float* att         = (const float*)d_in[4];
  float* out = (float*)d_out;

  char* ws = (char*)d_ws;
  size_t off = 0;
  auto alloc = [&](size_t bytes) { size_t o = off; off += (bytes + 255) & ~(size_t)255; return o; };

  float* Wh = (float*)(ws + alloc((size_t)NR * OUT_F * 4));           // 16.78 MB
  size_t regionOff = alloc((size_t)(NR + 1) * OUT_F * 4 * 2);          // 33.56 MB
  float* SufA = (float*)(ws + regionOff);
  float* PreB = (float*)(ws + regionOff + (size_t)(NR + 1) * OUT_F * 4);
  short* B3t  = (short*)(ws + regionOff);                              // 1.05 MB

  float* s1   = (float*)(ws + alloc(NR * 4));
  float* s2   = (float*)(ws + alloc(NR * 4));
  float* s2s  = (float*)(ws + alloc(NR * 4));
  int*   perm = (int*)  (ws + alloc(NR * 4));
  float* sufa = (float*)(ws + alloc((NR + 1) * 4));
  float* preb = (float*)(ws + alloc((NR + 1) * 4));
  float* eaA  = (float*)(ws + alloc(NR * 4));
  float* ebA  = (float*)(ws + alloc(NR * 4));
  float* chA  = (float*)(ws + alloc(NCH * OUT_F * 4));
  float* chB  = (float*)(ws + alloc(NCH * OUT_F * 4));

  k_prep<<<4096 + 1024, 256, 0, stream>>>(feat_edge, feat_edge_a, att, weight, s1, s2, B3t);
  k_gemm<<<256, 256, 0, stream>>>(feat_node_a, B3t, Wh);
  k_rank<<<NR / 8, 256, 0, stream>>>(s2, s2s, perm, eaA, ebA);
  k_passA<<<dim3(NCH + 1, 2), 256, 0, stream>>>(Wh, eaA, ebA, perm, chA, chB, sufa, preb);
  k_passC<<<dim3(NCH, 2), 256, 0, stream>>>(Wh, eaA, ebA, perm, chA, chB, SufA, PreB);
  k_final<<<NR / 4, 256, 0, stream>>>(s1, s2s, sufa, preb, SufA, PreB, out);
}